// Round 10
// baseline (478.507 us; speedup 1.0000x reference)
//
#include <hip/hip_runtime.h>

#define NP 22
#define NH 64
#define NL 5
#define NE 21

constexpr float CRc    = 3.0f;   // 15/L
constexpr float LOG2Mc = 7.0f;
constexpr float L2E    = 1.442695041f;

typedef __fp16 h2_t  __attribute__((ext_vector_type(2)));
typedef __fp16 f16x8 __attribute__((ext_vector_type(8)));
typedef float  f32x16 __attribute__((ext_vector_type(16)));

__device__ __forceinline__ float rcp_(float x) {
#if __has_builtin(__builtin_amdgcn_rcpf)
  return __builtin_amdgcn_rcpf(x);
#else
  float r; asm("v_rcp_f32 %0, %1" : "=v"(r) : "v"(x)); return r;
#endif
}
__device__ __forceinline__ float exp2_(float x) {
#if __has_builtin(__builtin_amdgcn_exp2f)
  return __builtin_amdgcn_exp2f(x);
#else
  float r; asm("v_exp_f32 %0, %1" : "=v"(r) : "v"(x)); return r;
#endif
}
__device__ __forceinline__ float sqrt_(float x) {
#if __has_builtin(__builtin_amdgcn_sqrtf)
  return __builtin_amdgcn_sqrtf(x);
#else
  float r; asm("v_sqrt_f32 %0, %1" : "=v"(r) : "v"(x)); return r;
#endif
}
__device__ __forceinline__ float sigf(float s)  { return rcp_(1.0f + exp2_(-L2E * s)); }
__device__ __forceinline__ float siluf(float s) { return s * sigf(s); }

__device__ __forceinline__ float rl_f(float v, int lane) {
  return __builtin_bit_cast(float, __builtin_amdgcn_readlane(__builtin_bit_cast(int, v), lane));
}
__device__ __forceinline__ h2_t rl_h2(h2_t v, int lane) {
  return __builtin_bit_cast(h2_t, __builtin_amdgcn_readlane(__builtin_bit_cast(int, v), lane));
}
__device__ __forceinline__ h2_t pkf(float a, float b) {
  return __builtin_amdgcn_cvt_pkrtz(a, b);
}
template <int CTRL>
__device__ __forceinline__ float dppmov(float v) {
  return __builtin_bit_cast(float,
      __builtin_amdgcn_update_dpp(0, __builtin_bit_cast(int, v), CTRL, 0xF, 0xF, true));
}
__device__ __forceinline__ float red32(float v) {
  v += dppmov<0xB1>(v);
  v += dppmov<0x4E>(v);
  v += dppmov<0x124>(v);
  v += dppmov<0x128>(v);
  v += __builtin_bit_cast(float, __builtin_amdgcn_ds_swizzle(
         __builtin_bit_cast(int, v), 0x401F));
  return v;
}
__device__ __forceinline__ float fdot2(h2_t a, h2_t b, float c) {
#if __has_builtin(__builtin_amdgcn_fdot2)
  return __builtin_amdgcn_fdot2(a, b, c, false);
#else
  float d;
  asm("v_dot2_f32_f16 %0, %1, %2, %3"
      : "=v"(d)
      : "v"(__builtin_bit_cast(int, a)), "v"(__builtin_bit_cast(int, b)), "v"(c));
  return d;
#endif
}

// LDS arena offsets (bytes)
#define OFF_WLDS   0        // 16384  B-fragment blocks (16 x 1KB)
#define OFF_AMG    16384    // 21632  169 rows x 32 words: 4 waves x 2 tiles x 21 rows + dump 168
#define OFF_HLDS   38016    // 5632   fp32 master h [22][64]
#define OFF_HIBUF  43648    // 5632   hi_part f32 / ubuf
#define OFF_HCBUF  49280    // 5632   hc_part f32
#define OFF_AGGU   54912    // 2816   agg f16 A-tile, then u16 A-tile
#define OFF_EAS    57728    // 1848   initial sq dists f32[462]
#define OFF_CBUF   59576    // 352    coords [22][4]
#define OFF_CUPD   59928    // 352    coord updates (vels at end)
#define OFF_VELM   60280    // 16
#define LDS_BYTES  60296

#define DUMPROW (168 * 32)

// ---- per-row edge-phase phases, A/B interleavable ----
#define STAGE_M1(TB, R, HII, RADT, EAT) do {                                \
  _Pragma("unroll")                                                         \
  for (int e2 = 0; e2 < 20; e2 += 2) {                                      \
    int ea_ = e2, eb_ = e2 + 1;                                             \
    int cola = ea_ + (ea_ >= (R)), colb = eb_ + (eb_ >= (R));               \
    float ra = rl_f((RADT), ea_), rb2 = rl_f((RADT), eb_);                  \
    float qa = rl_f((EAT), ea_),  qb = rl_f((EAT), eb_);                    \
    float s1a = (HII) + hcbuf[cola * 64 + lane];                            \
    s1a = fmaf(ra, w128r, s1a); s1a = fmaf(qa, w129r, s1a);                 \
    float s1b = (HII) + hcbuf[colb * 64 + lane];                            \
    s1b = fmaf(rb2, w128r, s1b); s1b = fmaf(qb, w129r, s1b);                \
    float m1a = siluf(s1a), m1b = siluf(s1b);                               \
    h2_t wa = pkf(m1a, dppmov<0xB1>(m1a));                                  \
    h2_t wb = pkf(dppmov<0xB1>(m1b), m1b);                                  \
    int row = (lane & 1) ? eb_ : ea_;                                       \
    int w = lane >> 1;                                                      \
    amg[(TB) + row * 32 + (w ^ ((row & 7) << 2))] =                         \
        (lane & 1) ? __builtin_bit_cast(int, wb) : __builtin_bit_cast(int, wa); \
  }                                                                         \
  {                                                                         \
    int col20 = 20 + (20 >= (R));                                           \
    float ra = rl_f((RADT), 20), qa = rl_f((EAT), 20);                      \
    float s1 = (HII) + hcbuf[col20 * 64 + lane];                            \
    s1 = fmaf(ra, w128r, s1); s1 = fmaf(qa, w129r, s1);                     \
    float m1 = siluf(s1);                                                   \
    h2_t wa = pkf(m1, dppmov<0xB1>(m1));                                    \
    if (!(lane & 1))                                                        \
      amg[(TB) + 20 * 32 + ((lane >> 1) ^ 16)] = __builtin_bit_cast(int, wa); \
  }                                                                         \
} while (0)

#define PASSMM(TB, B0, ACC0, ACC1) do {                                     \
  _Pragma("unroll")                                                         \
  for (int ii = 0; ii < 16; ++ii) { ACC0[ii] = 0.f; ACC1[ii] = 0.f; }       \
  _Pragma("unroll")                                                         \
  for (int ks = 0; ks < 4; ++ks) {                                          \
    int off = (ks * 8 + hh * 4) ^ ((c31 & 7) << 2);                         \
    f16x8 af = __builtin_bit_cast(f16x8, *(const int4*)&amg[(TB) + c31 * 32 + off]); \
    ACC0 = __builtin_amdgcn_mfma_f32_32x32x16_f16(af, bread((B0) + ks * 2 + 0), ACC0, 0, 0, 0); \
    ACC1 = __builtin_amdgcn_mfma_f32_32x32x16_f16(af, bread((B0) + ks * 2 + 1), ACC1, 0, 0, 0); \
  }                                                                         \
} while (0)

#define POST1(TB, ACC0, ACC1) do {                                          \
  _Pragma("unroll")                                                         \
  for (int q = 0; q < 16; ++q) {                                            \
    int e0 = (q & 3) + 8 * (q >> 2);                                        \
    int rowq = e0 + 4 * hh;                                                 \
    float m20 = siluf(ACC0[q] + b2r0);                                      \
    float m21 = siluf(ACC1[q] + b2r1);                                      \
    ACC0[q] = m20; ACC1[q] = m21;                                           \
    h2_t w0 = pkf(m20, dppmov<0xB1>(m20));                                  \
    h2_t w1 = pkf(dppmov<0xB1>(m21), m21);                                  \
    int wq = (lane & 1) ? 16 + (c31 >> 1) : (c31 >> 1);                     \
    int adr = (rowq < NE) ? ((TB) + rowq * 32 + (wq ^ ((rowq & 7) << 2)))   \
                          : (DUMPROW + wq);                                 \
    amg[adr] = (lane & 1) ? __builtin_bit_cast(int, w1)                     \
                          : __builtin_bit_cast(int, w0);                    \
  }                                                                         \
} while (0)

#define GATE(TB, SGT) do {                                                  \
  float gg = 0.f;                                                           \
  int xr = (c31 & 7) << 2;                                                  \
  _Pragma("unroll")                                                         \
  for (int tt = 0; tt < 8; ++tt) {                                          \
    int4 v4 = *(const int4*)&amg[(TB) + c31 * 32 + ((4 * tt) ^ xr)];        \
    gg = fdot2(__builtin_bit_cast(h2_t, v4.x), rl_h2(awT, 4 * tt + 0), gg); \
    gg = fdot2(__builtin_bit_cast(h2_t, v4.y), rl_h2(awT, 4 * tt + 1), gg); \
    gg = fdot2(__builtin_bit_cast(h2_t, v4.z), rl_h2(awT, 4 * tt + 2), gg); \
    gg = fdot2(__builtin_bit_cast(h2_t, v4.w), rl_h2(awT, 4 * tt + 3), gg); \
  }                                                                         \
  SGT = sigf(gg + abl);                                                     \
} while (0)

#define POST2A(TB, SGT, ACC0, ACC1, ACC2, ACC3, RROW, V) do {               \
  float aggn0 = 0.f, aggn1 = 0.f;                                           \
  _Pragma("unroll")                                                         \
  for (int q = 0; q < 16; ++q) {                                            \
    int e0 = (q & 3) + 8 * (q >> 2);                                        \
    int rowq = e0 + 4 * hh;                                                 \
    bool valid = (rowq < NE);                                               \
    float sg = hh ? rl_f(SGT, e0 + 4) : rl_f(SGT, e0);                      \
    aggn0 += valid ? ACC0[q] * sg : 0.f;                                    \
    aggn1 += valid ? ACC1[q] * sg : 0.f;                                    \
    float c10 = siluf(fmaf(sg, ACC2[q], cb1r0));                            \
    float c11 = siluf(fmaf(sg, ACC3[q], cb1r1));                            \
    h2_t w0 = pkf(c10, dppmov<0xB1>(c10));                                  \
    h2_t w1 = pkf(dppmov<0xB1>(c11), c11);                                  \
    int wq = (lane & 1) ? 16 + (c31 >> 1) : (c31 >> 1);                     \
    int adr = valid ? ((TB) + rowq * 32 + (wq ^ ((rowq & 7) << 2)))         \
                    : (DUMPROW + wq);                                       \
    amg[adr] = (lane & 1) ? __builtin_bit_cast(int, w1)                     \
                          : __builtin_bit_cast(int, w0);                    \
  }                                                                         \
  aggn0 += __shfl_xor(aggn0, 32, 64);                                       \
  aggn1 += __shfl_xor(aggn1, 32, 64);                                       \
  h2_t a0p = pkf(aggn0, dppmov<0xB1>(aggn0));                               \
  h2_t a1p = pkf(dppmov<0xB1>(aggn1), aggn1);                               \
  if ((V) && lane < 32) {                                                   \
    int wq = (lane & 1) ? 16 + (c31 >> 1) : (c31 >> 1);                     \
    aggu[(RROW) * 32 + (wq ^ (((RROW) & 7) << 2))] =                        \
        (lane & 1) ? __builtin_bit_cast(int, a1p) : __builtin_bit_cast(int, a0p); \
  }                                                                         \
} while (0)

#define CDOT(TB, DD) do {                                                   \
  DD = 0.f;                                                                 \
  int xr = (c31 & 7) << 2;                                                  \
  _Pragma("unroll")                                                         \
  for (int tt = 0; tt < 8; ++tt) {                                          \
    int4 v4 = *(const int4*)&amg[(TB) + c31 * 32 + ((4 * tt) ^ xr)];        \
    DD = fdot2(__builtin_bit_cast(h2_t, v4.x), rl_h2(c2T, 4 * tt + 0), DD); \
    DD = fdot2(__builtin_bit_cast(h2_t, v4.y), rl_h2(c2T, 4 * tt + 1), DD); \
    DD = fdot2(__builtin_bit_cast(h2_t, v4.z), rl_h2(c2T, 4 * tt + 2), DD); \
    DD = fdot2(__builtin_bit_cast(h2_t, v4.w), rl_h2(c2T, 4 * tt + 3), DD); \
  }                                                                         \
} while (0)

#define CEPI(DD, GX, GY, GZ, ND, RROW, V) do {                              \
  float th = 1.0f - 2.0f * rcp_(1.0f + exp2_(2.0f * L2E * (DD)));           \
  float ff = th * CRc * (ND);                                               \
  bool vlane = (lane < NE);                                                 \
  float cxc = vlane ? (GX) * ff : 0.f;                                      \
  float cyc = vlane ? (GY) * ff : 0.f;                                      \
  float czc = vlane ? (GZ) * ff : 0.f;                                      \
  cxc = red32(cxc); cyc = red32(cyc); czc = red32(czc);                     \
  if ((V) && lane < 3) {                                                    \
    float cv = (lane == 0) ? cxc : (lane == 1) ? cyc : czc;                 \
    cupd[(RROW) * 4 + lane] = cv;                                           \
  }                                                                         \
} while (0)

__global__ __launch_bounds__(256, 2) void egnn_kernel(
    const float* __restrict__ t,   const float* __restrict__ x,
    const float* __restrict__ embW, const float* __restrict__ embB,
    const float* __restrict__ ew1, const float* __restrict__ eb1,
    const float* __restrict__ ew2, const float* __restrict__ eb2,
    const float* __restrict__ nw1, const float* __restrict__ nb1,
    const float* __restrict__ nw2, const float* __restrict__ nb2,
    const float* __restrict__ cw1, const float* __restrict__ cb1,
    const float* __restrict__ cw2, const float* __restrict__ aw,
    const float* __restrict__ ab,  float* __restrict__ out)
{
  __shared__ __align__(16) char LDSRAW[LDS_BYTES];
  int*   wlds  = (int*)(LDSRAW + OFF_WLDS);
  int*   amg   = (int*)(LDSRAW + OFF_AMG);
  float* h_lds = (float*)(LDSRAW + OFF_HLDS);
  float* hibuf = (float*)(LDSRAW + OFF_HIBUF);
  float* hcbuf = (float*)(LDSRAW + OFF_HCBUF);
  int*   aggu  = (int*)(LDSRAW + OFF_AGGU);
  float* eas   = (float*)(LDSRAW + OFF_EAS);
  float* cbuf  = (float*)(LDSRAW + OFF_CBUF);
  float* cupd  = (float*)(LDSRAW + OFF_CUPD);
  float* velm  = (float*)(LDSRAW + OFF_VELM);

  const int b = blockIdx.x, tid = threadIdx.x;
  const int lane = tid & 63, wv = tid >> 6;
  const int c31 = lane & 31, hh = lane >> 5;
  const int xorv = ((lane >> 3) & 7) << 2;

  // 16-block fill: blocks [0,8) <- m0 rows, [8,16) <- m1 rows
  auto fillblk = [&](const float* m0, const float* m1, int nblocks) {
    for (int blk = wv; blk < nblocks; blk += 4) {
      const float* Ws = (blk < 8) ? m0 : m1;
      int kb = (blk >> 1) & 3, n = blk & 1;
      int k0 = kb * 16 + hh * 8;
      int ch = n * 32 + c31;
      int wb = blk * 256 + ((lane * 4) ^ xorv);
#pragma unroll
      for (int w = 0; w < 4; ++w) {
        h2_t p = pkf(Ws[(k0 + 2 * w) * NH + ch], Ws[(k0 + 2 * w + 1) * NH + ch]);
        wlds[wb + w] = __builtin_bit_cast(int, p);
      }
    }
  };
  auto bread = [&](int blk) -> f16x8 {
    return __builtin_bit_cast(f16x8, *(const int4*)&wlds[blk * 256 + ((lane * 4) ^ xorv)]);
  };
  auto aread = [&](const int* tile, int ks) -> f16x8 {
    int off = (ks * 8 + hh * 4) ^ ((c31 & 7) << 2);
    return __builtin_bit_cast(f16x8, *(const int4*)&tile[c31 * 32 + off]);
  };
  auto packh = [&]() {
    for (int idx = tid; idx < NP * 32; idx += 256) {
      int atom = idx >> 5, w = idx & 31;
      h2_t p = pkf(h_lds[atom * 64 + 2 * w], h_lds[atom * 64 + 2 * w + 1]);
      amg[atom * 32 + (w ^ ((atom & 7) << 2))] = __builtin_bit_cast(int, p);
    }
  };

  // ---- init
  if (tid < NP * 3) {
    int p = tid / 3, c = tid - p * 3;
    cbuf[p * 4 + c] = x[b * (NP * 3) + tid];
  }
  float tb = t[b];
  for (int p = wv; p < NP; p += 4)
    h_lds[p * 64 + lane] = embW[p * NH + lane] + tb * embW[22 * NH + lane]
                         + LOG2Mc * embW[23 * NH + lane] + embB[lane];
  __syncthreads();
  for (int idx = tid; idx < NP * NE; idx += 256) {
    int r = idx / NE, e = idx - r * NE, col = e + (e >= r);
    float dx = cbuf[r * 4 + 0] - cbuf[col * 4 + 0];
    float dy = cbuf[r * 4 + 1] - cbuf[col * 4 + 1];
    float dz = cbuf[r * 4 + 2] - cbuf[col * 4 + 2];
    eas[idx] = dx * dx + dy * dy + dz * dz;
  }
  __syncthreads();

  for (int l = 0; l < NL; ++l) {
    const float* W1 = ew1 + l * 130 * NH;
    const float* W2 = ew2 + l * NH * NH;
    const float* C1 = cw1 + l * NH * NH;
    const float* N1 = nw1 + l * 128 * NH;
    const float* N2 = nw2 + l * NH * NH;

    // step1: wlds <- W1lo(0-7), W1hi(8-15); pack h A-tile
    fillblk(W1, W1 + 64 * NH, 16);
    packh();
    __syncthreads();

    // step2: phase0 — hi (waves 0,1) / hc (waves 2,3)
    {
      int s = wv >> 1, n = wv & 1;
      f32x16 acc;
#pragma unroll
      for (int i = 0; i < 16; ++i) acc[i] = 0.f;
#pragma unroll
      for (int ks = 0; ks < 4; ++ks)
        acc = __builtin_amdgcn_mfma_f32_32x32x16_f16(aread(amg, ks),
                bread((s * 4 + ks) * 2 + n), acc, 0, 0, 0);
      int ch = n * 32 + c31;
      float bias = (s == 0) ? eb1[l * NH + ch] : 0.0f;
      float* dst = (s == 0) ? hibuf : hcbuf;
#pragma unroll
      for (int q = 0; q < 16; ++q) {
        int atom = (q & 3) + 8 * (q >> 2) + 4 * hh;
        if (atom < NP) dst[atom * 64 + ch] = acc[q] + bias;
      }
    }
    __syncthreads();

    // step3: wlds <- W2(0-7), C1(8-15)
    fillblk(W2, C1, 16);
    __syncthreads();

    // step4: edge phase — dual-row pipeline
    float w128r = W1[128 * NH + lane], w129r = W1[129 * NH + lane];
    float b2r0 = eb2[l * NH + c31],  b2r1 = eb2[l * NH + 32 + c31];
    float abl  = ab[l];
    float cb1r0 = cb1[l * NH + c31], cb1r1 = cb1[l * NH + 32 + c31];
    h2_t  awT  = pkf(aw[l * NH + 2 * c31],  aw[l * NH + 2 * c31 + 1]);
    h2_t  c2T  = pkf(cw2[l * NH + 2 * c31], cw2[l * NH + 2 * c31 + 1]);

    const int tA = wv * (2 * NE * 32);
    const int tB = tA + NE * 32;
#pragma unroll 1
    for (int i = 0; i < 3; ++i) {
      const int rA = wv + 8 * i;
      const int rB = rA + 4;
      const bool bval = (rB < NP);
      const int rBc = bval ? rB : NP - 1;

      // per-lane geometry (lane = edge)
      int eL = (lane < NE) ? lane : NE - 1;
      int colA = eL + (eL >= rA);
      int colB = eL + (eL >= rBc);
      float4 crA4 = *(const float4*)&cbuf[rA * 4];
      float4 ccA4 = *(const float4*)&cbuf[colA * 4];
      float4 crB4 = *(const float4*)&cbuf[rBc * 4];
      float4 ccB4 = *(const float4*)&cbuf[colB * 4];
      float gdxA = crA4.x - ccA4.x, gdyA = crA4.y - ccA4.y, gdzA = crA4.z - ccA4.z;
      float radA = gdxA * gdxA + gdyA * gdyA + gdzA * gdzA;
      float ndA  = rcp_(sqrt_(radA) + 1.0f);
      float gdxB = crB4.x - ccB4.x, gdyB = crB4.y - ccB4.y, gdzB = crB4.z - ccB4.z;
      float radB = gdxB * gdxB + gdyB * gdyB + gdzB * gdzB;
      float ndB  = rcp_(sqrt_(radB) + 1.0f);
      float eaTA = eas[rA * NE + eL];
      float eaTB = eas[rBc * NE + eL];
      float hiiA = hibuf[rA * 64 + lane];
      float hiiB = hibuf[rBc * 64 + lane];

      STAGE_M1(tA, rA, hiiA, radA, eaTA);
      STAGE_M1(tB, rBc, hiiB, radB, eaTB);

      f32x16 acc0A, acc1A, acc0B, acc1B;
      PASSMM(tA, 0, acc0A, acc1A);               // m1A @ W2
      PASSMM(tB, 0, acc0B, acc1B);               // m1B @ W2

      POST1(tA, acc0A, acc1A);
      POST1(tB, acc0B, acc1B);

      float sgA, sgB;
      GATE(tA, sgA);
      GATE(tB, sgB);

      {
        f32x16 acc2A, acc3A;
        PASSMM(tA, 8, acc2A, acc3A);             // m2A @ C1
        POST2A(tA, sgA, acc0A, acc1A, acc2A, acc3A, rA, true);
      }
      {
        f32x16 acc2B, acc3B;
        PASSMM(tB, 8, acc2B, acc3B);             // m2B @ C1
        POST2A(tB, sgB, acc0B, acc1B, acc2B, acc3B, rBc, bval);
      }

      float ddA, ddB;
      CDOT(tA, ddA);
      CDOT(tB, ddB);
      CEPI(ddA, gdxA, gdyA, gdzA, ndA, rA, true);
      CEPI(ddB, gdxB, gdyB, gdzB, ndB, rBc, bval);
    }
    __syncthreads();

    // step5: wlds <- N1lo(0-7), N1hi(8-15); repack h A-tile
    fillblk(N1, N1 + 64 * NH, 16);
    packh();
    __syncthreads();

    // step6: u = h@N1lo + agg@N1hi + nb1 -> hibuf (ubuf), waves 0,1
    if (wv < 2) {
      int n = wv;
      f32x16 acc;
#pragma unroll
      for (int i = 0; i < 16; ++i) acc[i] = 0.f;
#pragma unroll
      for (int ks = 0; ks < 4; ++ks)
        acc = __builtin_amdgcn_mfma_f32_32x32x16_f16(aread(amg, ks),
                bread(ks * 2 + n), acc, 0, 0, 0);
#pragma unroll
      for (int ks = 0; ks < 4; ++ks)
        acc = __builtin_amdgcn_mfma_f32_32x32x16_f16(aread(aggu, ks),
                bread((4 + ks) * 2 + n), acc, 0, 0, 0);
      float bias = nb1[l * NH + n * 32 + c31];
#pragma unroll
      for (int q = 0; q < 16; ++q) {
        int atom = (q & 3) + 8 * (q >> 2) + 4 * hh;
        if (atom < NP) hibuf[atom * 64 + n * 32 + c31] = acc[q] + bias;
      }
    }
    __syncthreads();

    // step7: wlds blocks 0-7 <- N2; u16 tile over aggu from silu(ubuf)
    fillblk(N2, N2, 8);
    for (int idx = tid; idx < NP * 32; idx += 256) {
      int atom = idx >> 5, w = idx & 31;
      h2_t p = pkf(siluf(hibuf[atom * 64 + 2 * w]), siluf(hibuf[atom * 64 + 2 * w + 1]));
      aggu[atom * 32 + (w ^ ((atom & 7) << 2))] = __builtin_bit_cast(int, p);
    }
    __syncthreads();

    // step8: h += u16@N2 + nb2 (waves 0,1); coords += cupd (waves 2,3)
    if (wv < 2) {
      int n = wv;
      f32x16 acc;
#pragma unroll
      for (int i = 0; i < 16; ++i) acc[i] = 0.f;
#pragma unroll
      for (int ks = 0; ks < 4; ++ks)
        acc = __builtin_amdgcn_mfma_f32_32x32x16_f16(aread(aggu, ks),
                bread(ks * 2 + n), acc, 0, 0, 0);
      int ch = n * 32 + c31;
      float bias = nb2[l * NH + ch];
#pragma unroll
      for (int q = 0; q < 16; ++q) {
        int atom = (q & 3) + 8 * (q >> 2) + 4 * hh;
        if (atom < NP) h_lds[atom * 64 + ch] += acc[q] + bias;
      }
    } else {
      int ci = tid - 128;
      if (ci < NP * 3) {
        int p = ci / 3, c = ci - 3 * p;
        cbuf[p * 4 + c] += cupd[p * 4 + c];
      }
    }
    __syncthreads();
  }

  // ---- output: vel = coord - coord0 (re-read x), mean-removed
  if (tid < NP * 3) {
    int p = tid / 3, c = tid - p * 3;
    cupd[p * 4 + c] = cbuf[p * 4 + c] - x[b * (NP * 3) + tid];
  }
  __syncthreads();
  if (tid < 3) {
    float s = 0.f;
    for (int p = 0; p < NP; ++p) s += cupd[p * 4 + tid];
    velm[tid] = s * (1.0f / 22.0f);
  }
  __syncthreads();
  if (tid < NP * 3) {
    int p = tid / 3, c = tid - p * 3;
    out[b * (NP * 3) + tid] = cupd[p * 4 + c] - velm[c];
  }
}

extern "C" void kernel_launch(void* const* d_in, const int* in_sizes, int n_in,
                              void* d_out, int out_size, void* d_ws, size_t ws_size,
                              hipStream_t stream) {
  const float* t    = (const float*)d_in[0];
  const float* x    = (const float*)d_in[1];
  const float* embW = (const float*)d_in[2];
  const float* embB = (const float*)d_in[3];
  // d_in[4] out_W, d_in[5] out_b: do not affect the returned velocities
  const float* ew1  = (const float*)d_in[6];
  const float* eb1  = (const float*)d_in[7];
  const float* ew2  = (const float*)d_in[8];
  const float* eb2  = (const float*)d_in[9];
  const float* nw1  = (const float*)d_in[10];
  const float* nb1  = (const float*)d_in[11];
  const float* nw2  = (const float*)d_in[12];
  const float* nb2  = (const float*)d_in[13];
  const float* cw1  = (const float*)d_in[14];
  const float* cb1  = (const float*)d_in[15];
  const float* cw2  = (const float*)d_in[16];
  const float* aw   = (const float*)d_in[17];
  const float* ab   = (const float*)d_in[18];
  // d_in[19] rows, d_in[20] cols: edge list regenerated analytically in-kernel

  egnn_kernel<<<1024, 256, 0, stream>>>(t, x, embW, embB, ew1, eb1, ew2, eb2,
                                        nw1, nb1, nw2, nb2, cw1, cb1, cw2,
                                        aw, ab, (float*)d_out);
}